// Round 6
// baseline (167.480 us; speedup 1.0000x reference)
//
#include <hip/hip_runtime.h>

// MoE_52037823758984: out[i] = x[i] @ W_{route[i]}^T + b_{route[i]}
// N = 2,097,152 tokens, D = 10, all f32 (route int32).
//
// R12 = "copy-mimic": erase ALL remaining structural deltas to the
// 6.3 TB/s float4-copy ubench in one bundled experiment.
//   Theory ledger: (1) per-wave pipelining dead (R8/R9, occupancy cost);
//   (2) nt-store L3 theory dead (R10, hint-invariant counters);
//   (3) load-side serialization dead (R11, structure-invariant).
//   Signature: 130MB fabric @ 2.45 TB/s, all pipes idle, time invariant
//   to in-wave structure -> memory-system limited. But the copy ubench
//   does 6.29 TB/s on the same chip, so 2.45 is NOT provably a ceiling.
//   Remaining deltas to copy structure, all removed here:
//     - one-shot 11-VMEM waves (16384 launches, 2 dispatch generations
//       with a drain/refill bubble)  -> 2048 blocks x 2 sequential chunks,
//       exactly one resident generation (8 blocks/CU, no LDS).
//     - LDS out-transpose + wave_barrier -> direct strided b128 stores.
//       PLAIN strided stores merge in write-back L2 via dirty-byte masks;
//       R5's 2.65x amplification was NT+strided (bypassed merge). PLAIN
//       strided is untested; WRITE_SIZE verifies instantly (~81920 KB
//       expected if clean).
//     - zero LDS, zero barriers, long(er)-lived waves issuing 22 VMEM.
//   Falsification: null at ~52us with clean counters kills the structure
//   hypothesis wholesale -> ~2.5 TB/s is the empirical system ceiling for
//   this 35/65 R/W mix -> declare roofline.
// Kept proven pieces: per-lane b128 loads at stride 80B (R11: zero fetch
// amplification), packed f2 math -> v_pk_fma_f32 (R5), VGPR must stay
// <64 (R8 cliff lesson).

#define BLOCK 256
#define D 10
#define WAVE_ROWS 128                         // rows per wave per chunk
#define CHUNK_ROWS 512                        // rows per block per chunk
#define GRID_BLOCKS 2048                      // one resident generation

typedef float f4 __attribute__((ext_vector_type(4)));
typedef float f2 __attribute__((ext_vector_type(2)));

__global__ __launch_bounds__(BLOCK) void moe_kernel(
    const float* __restrict__ x,
    const float* __restrict__ W1,
    const float* __restrict__ b1,
    const float* __restrict__ W2,
    const float* __restrict__ b2,
    const int*   __restrict__ route,
    float*       __restrict__ out,
    int n)
{
    const int lane = threadIdx.x & 63;
    const int wave = threadIdx.x >> 6;

    const int nchunks = (n + CHUNK_ROWS - 1) / CHUNK_ROWS;  // 4096

    for (int c = blockIdx.x; c < nchunks; c += gridDim.x) {
        const long long rowbase =
            (long long)c * CHUNK_ROWS + wave * WAVE_ROWS;

        if (rowbase + WAVE_ROWS <= n) {
            // ---- direct per-lane loads: rows 2L, 2L+1 (5x b128 @80B) ----
            // base 16B-aligned; every byte of the wave's 5KB span is
            // consumed -> zero fetch amplification (R11-verified).
            const f4* __restrict__ xv = (const f4*)(x + rowbase * D);
            const int2 rt = ((const int2*)(route + rowbase))[lane];

            float xf[2 * D];
            #pragma unroll
            for (int j = 0; j < 5; ++j) {
                f4 t = xv[lane * 5 + j];
                xf[4 * j + 0] = t.x; xf[4 * j + 1] = t.y;
                xf[4 * j + 2] = t.z; xf[4 * j + 3] = t.w;
            }

            // row-pair vectors: xp[k] = (row0[k], row1[k])
            f2 xp[D];
            #pragma unroll
            for (int k = 0; k < D; ++k)
                xp[k] = (f2){xf[k], xf[D + k]};

            // ---- packed MLP: both experts, route-select ----
            float o0[D], o1[D];
            #pragma unroll
            for (int j = 0; j < D; ++j) {
                f2 a0 = (f2){b1[j], b1[j]};
                f2 a1 = (f2){b2[j], b2[j]};
                #pragma unroll
                for (int k = 0; k < D; ++k) {
                    const float w1 = W1[j * D + k];
                    const float w2 = W2[j * D + k];
                    a0 = __builtin_elementwise_fma(xp[k], (f2){w1, w1}, a0);
                    a1 = __builtin_elementwise_fma(xp[k], (f2){w2, w2}, a1);
                }
                o0[j] = rt.x ? a1.x : a0.x;
                o1[j] = rt.y ? a1.y : a0.y;
            }

            // ---- direct strided b128 PLAIN stores (no LDS, no barrier) --
            // Wave's 5 instrs tile a contiguous 5KB span; write-back L2
            // merges partial lines (dirty-byte masks). WRITE_SIZE is the
            // amplification check.
            f4* __restrict__ ov = (f4*)(out + rowbase * D);
            #pragma unroll
            for (int j = 0; j < 5; ++j) {
                f4 t;
                t.x = (j < 2) ? o0[4 * j + 0]
                    : (j == 2 ? o0[8] : o1[4 * (j - 3) + 2]);
                // build tuples explicitly (clearer than the ?: ladder):
                (void)t;
                f4 s;
                switch (j) {
                    case 0: s = (f4){o0[0], o0[1], o0[2], o0[3]}; break;
                    case 1: s = (f4){o0[4], o0[5], o0[6], o0[7]}; break;
                    case 2: s = (f4){o0[8], o0[9], o1[0], o1[1]}; break;
                    case 3: s = (f4){o1[2], o1[3], o1[4], o1[5]}; break;
                    default: s = (f4){o1[6], o1[7], o1[8], o1[9]}; break;
                }
                ov[lane * 5 + j] = s;
            }
        } else {
            // ---- tail path (not hit for N=2097152) ----
            for (int r = 0; r < 2; ++r) {
                const long long row = rowbase + lane * 2 + r;
                if (row < n) {
                    const int sel = route[row];
                    for (int j = 0; j < D; ++j) {
                        float y0 = b1[j];
                        float y1 = b2[j];
                        for (int k = 0; k < D; ++k) {
                            const float xk = x[row * D + k];
                            y0 = fmaf(xk, W1[j * D + k], y0);
                            y1 = fmaf(xk, W2[j * D + k], y1);
                        }
                        out[row * D + j] = sel ? y1 : y0;
                    }
                }
            }
        }
    }
}

extern "C" void kernel_launch(void* const* d_in, const int* in_sizes, int n_in,
                              void* d_out, int out_size, void* d_ws, size_t ws_size,
                              hipStream_t stream) {
    const float* x     = (const float*)d_in[0];
    const float* W1    = (const float*)d_in[1];
    const float* b1    = (const float*)d_in[2];
    const float* W2    = (const float*)d_in[3];
    const float* b2    = (const float*)d_in[4];
    const int*   route = (const int*)d_in[5];
    float*       out   = (float*)d_out;

    const int n = in_sizes[5];  // N tokens (route length)
    const int nchunks = (n + CHUNK_ROWS - 1) / CHUNK_ROWS;
    const int blocks = nchunks < GRID_BLOCKS ? nchunks : GRID_BLOCKS;

    moe_kernel<<<blocks, BLOCK, 0, stream>>>(x, W1, b1, W2, b2, route, out, n);
}